// Round 2
// baseline (1493.514 us; speedup 1.0000x reference)
//
#include <hip/hip_runtime.h>
#include <hip/hip_fp16.h>

typedef __attribute__((ext_vector_type(8))) short  s16x8;   // 8x16-bit (4 VGPRs)
typedef __attribute__((ext_vector_type(4))) float  f32x4;   // MFMA C/D frag
typedef __attribute__((ext_vector_type(4))) unsigned short u16x4;
typedef _Float16 f16x2 __attribute__((ext_vector_type(2)));
typedef _Float16 f16x8 __attribute__((ext_vector_type(8)));
typedef unsigned short u16;

#define MFMA16B(A, B, C) __builtin_amdgcn_mfma_f32_16x16x32_bf16((A), (B), (C), 0, 0, 0)
#define MFMA16H(A, B, C) __builtin_amdgcn_mfma_f32_16x16x32_f16((A), (B), (C), 0, 0, 0)

static __device__ __forceinline__ u16 f2bf(float f) {
    union { float f; unsigned u; } v; v.f = f;
    unsigned r = (v.u + 0x7fffu + ((v.u >> 16) & 1u)) >> 16;   // RNE
    return (u16)r;
}

static __device__ __forceinline__ s16x8 pack_f16x8(float4 a, float4 b) {
    s16x8 r;
    r[0] = (short)__half_as_ushort(__float2half_rn(a.x));
    r[1] = (short)__half_as_ushort(__float2half_rn(a.y));
    r[2] = (short)__half_as_ushort(__float2half_rn(a.z));
    r[3] = (short)__half_as_ushort(__float2half_rn(a.w));
    r[4] = (short)__half_as_ushort(__float2half_rn(b.x));
    r[5] = (short)__half_as_ushort(__float2half_rn(b.y));
    r[6] = (short)__half_as_ushort(__float2half_rn(b.z));
    r[7] = (short)__half_as_ushort(__float2half_rn(b.w));
    return r;
}

static __device__ __forceinline__ unsigned pk2f16(float a, float b) {
    unsigned lo = __half_as_ushort(__float2half_rn(a));
    unsigned hi = __half_as_ushort(__float2half_rn(b));
    return lo | (hi << 16);
}

static __device__ __forceinline__ float hu2f(u16 v) {
    __half_raw hr; hr.x = v; return __half2float(__half(hr));
}

// 2-way f16 dot with f32 accumulate: v_dot2_f32_f16.
static __device__ __forceinline__ float dot2(unsigned a, unsigned b, float c) {
#if __has_builtin(__builtin_amdgcn_fdot2)
    return __builtin_amdgcn_fdot2(__builtin_bit_cast(f16x2, a),
                                  __builtin_bit_cast(f16x2, b), c, false);
#else
    f16x2 av = __builtin_bit_cast(f16x2, a), bv = __builtin_bit_cast(f16x2, b);
    return fmaf((float)av[0], (float)bv[0], fmaf((float)av[1], (float)bv[1], c));
#endif
}

// fast sigmoid / tanh via v_exp + v_rcp (saturating, NaN-free at extremes)
static __device__ __forceinline__ float sigm(float x) {
    return __builtin_amdgcn_rcpf(1.f + __expf(-x));
}
static __device__ __forceinline__ float tanh_f(float x) {
    float e = __expf(-2.f * x);          // x->-inf: e=inf -> rcp=0 -> -1; x->+inf: e=0 -> +1
    return fmaf(2.f, __builtin_amdgcn_rcpf(1.f + e), -1.f);
}

// LDS-only workgroup barrier (no vmcnt drain -> xg prefetch stays in flight).
static __device__ __forceinline__ void wg_barrier() {
    asm volatile("s_waitcnt lgkmcnt(0)\n\ts_barrier" ::: "memory");
}

// ---------------------------------------------------------------------------
// K1: x_gates[m=131072][512] (fp16) = x[m][300] @ W_ih^T + (b_ih + b_hh)
// grid (4, 1024): 4 n-blocks sharing an x-tile are dispatch-adjacent (L2 reuse).
// ---------------------------------------------------------------------------
__global__ __launch_bounds__(256, 2)
void k1_gemm_xgates(const float* __restrict__ x, const float* __restrict__ W_ih,
                    const float* __restrict__ b_ih, const float* __restrict__ b_hh,
                    __half* __restrict__ xg) {
    const int n0 = blockIdx.x * 128;       // 4 blocks
    const int m0 = blockIdx.y * 128;       // 1024 blocks
    const int tid = threadIdx.x;
    const int wave = tid >> 6, lane = tid & 63;
    const int lanelo = lane & 15, quad = lane >> 4;
    const int mw = (wave & 1) * 64, nw = (wave >> 1) * 64;

    __shared__ __align__(16) u16 As[128 * 40];
    __shared__ __align__(16) u16 Bs[128 * 40];

    f32x4 acc[4][4];
#pragma unroll
    for (int i = 0; i < 4; ++i)
#pragma unroll
        for (int j = 0; j < 4; ++j) acc[i][j] = (f32x4)0.f;

    const int srow = tid >> 1;
    const int scol = (tid & 1) * 16;

    for (int kc = 0; kc < 10; ++kc) {
        const int k0 = kc * 32;
        const float* srcA = x + (size_t)(m0 + srow) * 300 + k0 + scol;
        const float* srcB = W_ih + (size_t)(n0 + srow) * 300 + k0 + scol;
        if (kc < 9) {                       // full chunk, no bounds checks
#pragma unroll
            for (int i = 0; i < 4; ++i) {
                const int col = scol + i * 4;
                float4 v = *(const float4*)(srcA + i * 4);
                u16x4 w; w.x = f2bf(v.x); w.y = f2bf(v.y); w.z = f2bf(v.z); w.w = f2bf(v.w);
                *(u16x4*)&As[srow * 40 + col] = w;
                float4 u = *(const float4*)(srcB + i * 4);
                u16x4 q; q.x = f2bf(u.x); q.y = f2bf(u.y); q.z = f2bf(u.z); q.w = f2bf(u.w);
                *(u16x4*)&Bs[srow * 40 + col] = q;
            }
        } else {                            // tail chunk (K 288..299, rest zero)
#pragma unroll
            for (int i = 0; i < 4; ++i) {
                const int col = scol + i * 4;
                float4 v = {0.f, 0.f, 0.f, 0.f}, u = {0.f, 0.f, 0.f, 0.f};
                if (k0 + col + 3 < 300) { v = *(const float4*)(srcA + i * 4);
                                          u = *(const float4*)(srcB + i * 4); }
                u16x4 w; w.x = f2bf(v.x); w.y = f2bf(v.y); w.z = f2bf(v.z); w.w = f2bf(v.w);
                *(u16x4*)&As[srow * 40 + col] = w;
                u16x4 q; q.x = f2bf(u.x); q.y = f2bf(u.y); q.z = f2bf(u.z); q.w = f2bf(u.w);
                *(u16x4*)&Bs[srow * 40 + col] = q;
            }
        }
        __syncthreads();

        s16x8 af[4], bf[4];
#pragma unroll
        for (int mt = 0; mt < 4; ++mt)
            af[mt] = *(const s16x8*)&As[(mw + mt * 16 + lanelo) * 40 + quad * 8];
#pragma unroll
        for (int nt = 0; nt < 4; ++nt)
            bf[nt] = *(const s16x8*)&Bs[(nw + nt * 16 + lanelo) * 40 + quad * 8];
#pragma unroll
        for (int mt = 0; mt < 4; ++mt)
#pragma unroll
            for (int nt = 0; nt < 4; ++nt)
                acc[mt][nt] = MFMA16B(af[mt], bf[nt], acc[mt][nt]);
        __syncthreads();
    }

#pragma unroll
    for (int nt = 0; nt < 4; ++nt) {
        const int n = n0 + nw + nt * 16 + lanelo;
        const float bs = b_ih[n] + b_hh[n];
#pragma unroll
        for (int mt = 0; mt < 4; ++mt) {
            const int mr = m0 + mw + mt * 16 + quad * 4;
#pragma unroll
            for (int r = 0; r < 4; ++r)
                xg[(size_t)(mr + r) * 512 + n] = __float2half(acc[mt][nt][r] + bs);
        }
    }
}

// ---------------------------------------------------------------------------
// K2 v5: LSTM recurrence, 2 batch rows per WG, software-pipelined.
//   64 WGs x 256 threads. Lane pairing: gp = lane&1; thread pair (2j, 2j+1)
//   owns column hj = wave*32 + j. gp=0 holds gate rows {i: hj, f: 128+hj},
//   gp=1 holds {g: 256+hj, o: 384+hj}. W_hh stationary in VGPRs (128 dwords,
//   SHARED across both batch rows). Gate exchange = 2x __shfl_xor(.,1) (DPP),
//   no LDS round-trip. Per iteration:
//     dotA(t) || cellB(t-1)  -> bar (hB visible)
//     dotB(t) || cellA(t)    -> bar (hA visible)
//   = 1 barrier per row-step; each row's serial cell-update chain hides under
//   the partner row's 256-cycle issue-bound dot stream. xg staged 8 steps x
//   2 rows per chunk with register prefetch (vmcnt never drained at barriers).
// ---------------------------------------------------------------------------
__global__ __launch_bounds__(256, 1)
void k2_lstm_rec(const __half* __restrict__ xg_all, const float* __restrict__ W_hh,
                 __half* __restrict__ h_seq) {
    const int blk = blockIdx.x;            // 0..63 -> batch rows 2*blk, 2*blk+1
    const int tid = threadIdx.x;
    const int w = tid >> 6, l = tid & 63;
    const int gp = l & 1;                  // 0: i,f   1: g,o
    const int hj = w * 32 + (l >> 1);      // owned h column 0..127

    __shared__ __align__(16) unsigned hA_pk[64];   // 128 f16 h for row A
    __shared__ __align__(16) unsigned hB_pk[64];   // 128 f16 h for row B
    __shared__ __align__(16) u16 xgA[8][512];      // 8-step xg chunk, row A
    __shared__ __align__(16) u16 xgB[8][512];      // 8-step xg chunk, row B

    const int r0 = gp * 256 + hj;          // i (gp0) or g (gp1)
    const int r1 = r0 + 128;               // f (gp0) or o (gp1)

    // --- stationary W_hh rows (f32 -> packed f16 pairs in VGPRs), shared A/B
    unsigned w0[64], w1[64];
    {
        const float* r0p = W_hh + (size_t)r0 * 128;
        const float* r1p = W_hh + (size_t)r1 * 128;
#pragma unroll
        for (int k = 0; k < 64; ++k) {
            float2 a = ((const float2*)r0p)[k];
            float2 b = ((const float2*)r1p)[k];
            w0[k] = pk2f16(a.x, a.y);
            w1[k] = pk2f16(b.x, b.y);
        }
    }

    // branchless activation constants: u = sb*sigm(sb*x)+bb
    //   gp0: 1*sigm(x)+0 = sigm(x);  gp1: 2*sigm(2x)-1 = tanh(x)
    const float sb = gp ? 2.f : 1.f;
    const float bb = gp ? -1.f : 0.f;

    // --- xg chunk staging map: 256 threads x 32 B cover 8 steps x 512 u16 (per row)
    const int pS = tid >> 5;               // step within chunk
    const int cS = (tid & 31) * 16;        // u16 column
    const size_t rA = (size_t)(blk * 2), rB = rA + 1;
    const u16* srcA = (const u16*)xg_all + rA * 1024 * 512 + (size_t)pS * 512 + cS;
    const u16* srcB = (const u16*)xg_all + rB * 1024 * 512 + (size_t)pS * 512 + cS;

    // prime chunk 0 (both rows) + zero h state
    s16x8 xA0 = *(const s16x8*)srcA;
    s16x8 xA1 = *(const s16x8*)(srcA + 8);
    s16x8 xB0 = *(const s16x8*)srcB;
    s16x8 xB1 = *(const s16x8*)(srcB + 8);
    if (tid < 64) { hA_pk[tid] = 0u; hB_pk[tid] = 0u; }
    *(s16x8*)&xgA[pS][cS]     = xA0;
    *(s16x8*)&xgA[pS][cS + 8] = xA1;
    *(s16x8*)&xgB[pS][cS]     = xB0;
    *(s16x8*)&xgB[pS][cS + 8] = xB1;
    __syncthreads();

    float cC  = 0.f;                       // cell state: gp0 lanes = row A, gp1 lanes = row B
    float pB0 = 0.f, pB1 = 0.f;            // carried row-B preactivations
    __half* houtA = h_seq + rA * 1024 * 128 + hj;
    __half* houtB = h_seq + rB * 1024 * 128 + hj;

#define DOT128(HPK, O0, O1, X0, X1) do {                                        \
        const uint4* _hp = (const uint4*)(HPK);                                 \
        float _s0 = 0.f, _s1 = 0.f, _s2 = 0.f, _s3 = 0.f;                       \
        _Pragma("unroll")                                                       \
        for (int _j = 0; _j < 16; ++_j) {                                       \
            const uint4 _hv = _hp[_j];                                          \
            const int _k = _j * 4;                                              \
            _s0 = dot2(w0[_k + 0], _hv.x, _s0); _s2 = dot2(w1[_k + 0], _hv.x, _s2); \
            _s1 = dot2(w0[_k + 1], _hv.y, _s1); _s3 = dot2(w1[_k + 1], _hv.y, _s3); \
            _s0 = dot2(w0[_k + 2], _hv.z, _s0); _s2 = dot2(w1[_k + 2], _hv.z, _s2); \
            _s1 = dot2(w0[_k + 3], _hv.w, _s1); _s3 = dot2(w1[_k + 3], _hv.w, _s3); \
        }                                                                       \
        O0 = _s0 + _s1 + (X0);                                                  \
        O1 = _s2 + _s3 + (X1);                                                  \
    } while (0)

    for (int t0 = 0; t0 < 1024; t0 += 8) {
        const bool have_next = (t0 + 8) < 1024;
        if (have_next) {                   // register prefetch; barriers don't drain it
            const u16* sA = srcA + (size_t)(t0 + 8) * 512;
            const u16* sB = srcB + (size_t)(t0 + 8) * 512;
            xA0 = *(const s16x8*)sA;  xA1 = *(const s16x8*)(sA + 8);
            xB0 = *(const s16x8*)sB;  xB1 = *(const s16x8*)(sB + 8);
        }
        for (int p = 0; p < 8; ++p) {
            const int t = t0 + p;

            // ---- phase A: dot over hA(t-1); overlapped: cellB(t-1) ----
            float qa0, qa1;
            {
                const float xa0 = hu2f(xgA[p][r0]);
                const float xa1 = hu2f(xgA[p][r1]);
                DOT128(hA_pk, qa0, qa1, xa0, xa1);
            }
            if (t > 0) {                   // cellB(t-1): update row B (gp1 lanes)
                const float u0 = fmaf(sb, sigm(sb * pB0), bb);   // gp0: si, gp1: tg
                const float u1 = sigm(pB1);                      // gp0: sf, gp1: so
                const float v0 = __shfl_xor(u0, 1);
                const float v1 = __shfl_xor(u1, 1);
                if (gp) {                  // c = sf*c + si*tg ; h = so*tanh(c)
                    cC = fmaf(v1, cC, v0 * u0);
                    const float hB = u1 * tanh_f(cC);
                    const __half hh = __float2half(hB);
                    ((u16*)hB_pk)[hj] = (u16)__half_as_ushort(hh);
                    houtB[(size_t)(t - 1) * 128] = hh;           // fire-and-forget
                }
            }
            wg_barrier();                  // hB(t-1) visible

            // ---- phase B: dot over hB(t-1); overlapped: cellA(t) ----
            {
                const float xb0 = hu2f(xgB[p][r0]);
                const float xb1 = hu2f(xgB[p][r1]);
                DOT128(hB_pk, pB0, pB1, xb0, xb1);   // carried to next iteration
            }
            {                              // cellA(t): update row A (gp0 lanes)
                const float u0 = fmaf(sb, sigm(sb * qa0), bb);   // gp0: si, gp1: tg
                const float u1 = sigm(qa1);                      // gp0: sf, gp1: so
                const float v0 = __shfl_xor(u0, 1);
                const float v1 = __shfl_xor(u1, 1);
                if (!gp) {                 // c = sf*c + si*tg ; h = so*tanh(c)
                    cC = fmaf(u1, cC, u0 * v0);
                    const float hA = v1 * tanh_f(cC);
                    const __half hh = __float2half(hA);
                    ((u16*)hA_pk)[hj] = (u16)__half_as_ushort(hh);
                    houtA[(size_t)t * 128] = hh;                 // fire-and-forget
                }
            }
            wg_barrier();                  // hA(t) visible
        }
        if (have_next) {                   // xr regs -> LDS (vmcnt waited here only)
            *(s16x8*)&xgA[pS][cS]     = xA0;
            *(s16x8*)&xgA[pS][cS + 8] = xA1;
            *(s16x8*)&xgB[pS][cS]     = xB0;
            *(s16x8*)&xgB[pS][cS + 8] = xB1;
            wg_barrier();
        }
    }

    // epilogue: cellB(1023)
    {
        const float u0 = fmaf(sb, sigm(sb * pB0), bb);
        const float u1 = sigm(pB1);
        const float v0 = __shfl_xor(u0, 1);
        const float v1 = __shfl_xor(u1, 1);
        if (gp) {
            cC = fmaf(v1, cC, v0 * u0);
            houtB[(size_t)1023 * 128] = __float2half(u1 * tanh_f(cC));
        }
    }
#undef DOT128
}

// ---------------------------------------------------------------------------
// K3: y[m=131072][64] = h_seq(f16)[m][128] @ W1^T + b1   (f16 MFMA)
// ---------------------------------------------------------------------------
__global__ __launch_bounds__(256, 2)
void k3_gemm_out(const u16* __restrict__ hseq, const float* __restrict__ W1,
                 const float* __restrict__ b1, float* __restrict__ y) {
    const int m0 = blockIdx.x * 128;
    const int tid = threadIdx.x;
    const int wave = tid >> 6, lane = tid & 63;
    const int lanelo = lane & 15, quad = lane >> 4;

    __shared__ __align__(16) u16 Ah[128 * 136];
    __shared__ __align__(16) u16 Bw[64 * 136];
    __shared__ float b1s[64];

    {
        const int row = tid >> 1, cg = (tid & 1) * 64;
        const u16* src = hseq + (size_t)(m0 + row) * 128 + cg;
#pragma unroll
        for (int i = 0; i < 8; ++i)
            *(s16x8*)&Ah[row * 136 + cg + i * 8] = *(const s16x8*)(src + i * 8);
    }
    {
        const int row = tid >> 2, cg = (tid & 3) * 32;
        const float* src = W1 + (size_t)row * 128 + cg;
#pragma unroll
        for (int i = 0; i < 4; ++i) {
            float4 v0 = *(const float4*)(src + i * 8);
            float4 v1 = *(const float4*)(src + i * 8 + 4);
            *(s16x8*)&Bw[row * 136 + cg + i * 8] = pack_f16x8(v0, v1);
        }
    }
    if (tid < 64) b1s[tid] = b1[tid];
    __syncthreads();

    f16x8 af[2][4], bf[4][4];
#pragma unroll
    for (int mt = 0; mt < 2; ++mt)
#pragma unroll
        for (int kt = 0; kt < 4; ++kt)
            af[mt][kt] = __builtin_bit_cast(f16x8,
                *(const s16x8*)&Ah[(wave * 32 + mt * 16 + lanelo) * 136 + kt * 32 + quad * 8]);
#pragma unroll
    for (int nt = 0; nt < 4; ++nt)
#pragma unroll
        for (int kt = 0; kt < 4; ++kt)
            bf[nt][kt] = __builtin_bit_cast(f16x8,
                *(const s16x8*)&Bw[(nt * 16 + lanelo) * 136 + kt * 32 + quad * 8]);

    f32x4 acc[2][4];
#pragma unroll
    for (int mt = 0; mt < 2; ++mt)
#pragma unroll
        for (int nt = 0; nt < 4; ++nt) acc[mt][nt] = (f32x4)0.f;
#pragma unroll
    for (int kt = 0; kt < 4; ++kt)
#pragma unroll
        for (int mt = 0; mt < 2; ++mt)
#pragma unroll
            for (int nt = 0; nt < 4; ++nt)
                acc[mt][nt] = MFMA16H(af[mt][kt], bf[nt][kt], acc[mt][nt]);

#pragma unroll
    for (int mt = 0; mt < 2; ++mt)
#pragma unroll
        for (int nt = 0; nt < 4; ++nt) {
            const int n = nt * 16 + lanelo;
            const float bs = b1s[n];
            const int mr = m0 + wave * 32 + mt * 16 + quad * 4;
#pragma unroll
            for (int r = 0; r < 4; ++r)
                y[(size_t)(mr + r) * 64 + n] = acc[mt][nt][r] + bs;
        }
}

// ---------------------------------------------------------------------------
extern "C" void kernel_launch(void* const* d_in, const int* in_sizes, int n_in,
                              void* d_out, int out_size, void* d_ws, size_t ws_size,
                              hipStream_t stream) {
    const float* x    = (const float*)d_in[0];
    const float* W_ih = (const float*)d_in[1];
    const float* W_hh = (const float*)d_in[2];
    const float* b_ih = (const float*)d_in[3];
    const float* b_hh = (const float*)d_in[4];
    const float* W1   = (const float*)d_in[5];
    const float* b1   = (const float*)d_in[6];
    float* y = (float*)d_out;

    const size_t XG_BYTES = (size_t)131072 * 512 * 2;   // x_gates fp16: 134 MB
    const size_t HS_BYTES = (size_t)131072 * 128 * 2;   // h_seq  fp16:  33.5 MB
    if (ws_size < XG_BYTES + HS_BYTES) return;

    __half* xg   = (__half*)d_ws;
    __half* hseq = (__half*)((char*)d_ws + XG_BYTES);

    k1_gemm_xgates<<<dim3(4, 1024), 256, 0, stream>>>(x, W_ih, b_ih, b_hh, xg);
    k2_lstm_rec<<<64, 256, 0, stream>>>(xg, W_hh, hseq);
    k3_gemm_out<<<1024, 256, 0, stream>>>((const u16*)hseq, W1, b1, y);
}